// Round 1
// 147.953 us; speedup vs baseline: 1.0249x; 1.0249x over previous
//
#include <hip/hip_runtime.h>
#include <math.h>

#define T_TGT 50
#define NCLS 80
#define NBATCH 16

// blocks per batch per layer: ceil(3*H*H / 256)
#define NB_L0 5     // 3*19*19 = 1083
#define NB_L1 17    // 3*38*38 = 4332
#define NB_L2 68    // 3*76*76 = 17328
#define NB_MAIN ((NB_L0 + NB_L1 + NB_L2) * NBATCH)   // 1440
#define N_CLS_UNITS (T_TGT * NBATCH * 3)             // 2400
#define NB_CLS ((N_CLS_UNITS + 3) / 4)               // 600 (4 waves/block)
#define NB_TOTAL (NB_MAIN + NB_CLS)                  // 2040

// NOTE (R4 post-mortem, prev session): do NOT use a per-block device-scope
// atomic/fence finish pattern here — 2040 single-address device atomics +
// __threadfence (L2 writeback on non-coherent XCD L2s) serialize at ~25ns
// each = +40us. Two stream-ordered nodes are cheaper.

__constant__ float c_anchors[18] = {10,13,16,30,33,23,30,61,62,45,
                                    59,119,116,90,156,198,373,326};

__device__ __forceinline__ float softplusf(float x){
    return fmaxf(x, 0.f) + log1pf(expf(-fabsf(x)));
}
__device__ __forceinline__ float bcef(float x, float t){
    return t * softplusf(-x) + (1.f - t) * softplusf(x);
}

// SoA shared layout: aligned float4 boxes (ds_read_b128 broadcast),
// winner metadata indexed by ORIGINAL target idx (read once, at the end),
// per-cell winner map filled by scatter instead of scanned in the hot loop.
struct SmemMain {
    float4 box[T_TGT];   // compacted: valid targets only
    float  thr[T_TGT];   // compacted: 0.7 * truth_area
    float  fx[T_TGT];    // by original t
    float  fy[T_TGT];
    float  lw[T_TGT];
    float  lh[T_TGT];
    float  w2[T_TGT];
    int    win[256];     // per-cell winning target idx, -1 if none
    int    nval;
};

template<int H, int STRIDE, int GROUP>
__device__ float main_cells(const float* __restrict__ raw,
                            const float* __restrict__ targets,
                            int b, int cb, int tid, SmemMain* sm)
{
    constexpr int HH = H * H;
    constexpr int CELLS = 3 * HH;

    // ---- issue the 5 channel loads FIRST so they overlap the target
    //      preprocessing + barriers (compiler won't hoist across s_barrier)
    const int c = cb * 256 + tid;
    const bool cell_ok = (c < CELLS);
    int a = 0, j = 0, i = 0;
    float x0 = 0.f, x1 = 0.f, x2 = 0.f, x3 = 0.f, x4 = 0.f;
    if (cell_ok) {
        a = c / HH;
        const int rem = c - a * HH;
        j = rem / H;
        i = rem - j * H;
        const float* base = raw + ((size_t)b * 255 + a * 85) * HH + rem;
        x0 = base[0];
        x1 = base[HH];
        x2 = base[2 * HH];
        x3 = base[3 * HH];
        x4 = base[4 * HH];
    }

    sm->win[tid] = -1;

    // ---- per-target metadata + valid-compaction (wave 0 only)
    bool scat = false; int rel = 0;
    if (tid < 64) {
        bool valid = false;
        float tx = 0.f, ty = 0.f, tw = 0.f, th = 0.f, tarea = 0.f;
        int bestn = 0;
        if (tid < T_TGT) {
            const float* lab = targets + ((size_t)b * T_TGT + tid) * 5;
            float cf = lab[0], x = lab[1], y = lab[2], w = lab[3], h = lab[4];
            valid = (cf + x + y + w + h) > 0.f;
            const float fs = (float)H;
            tx = x * fs; ty = y * fs; tw = w * fs; th = h * fs;
            tarea = tw * th;
            float best = -1.f;
            #pragma unroll
            for (int n = 0; n < 9; n++) {
                float aw = c_anchors[2*n]   * (1.f / STRIDE);
                float ah = c_anchors[2*n+1] * (1.f / STRIDE);
                float mw = fminf(tw, aw), mh = fminf(th, ah);
                float inter = (mw > 0.f && mh > 0.f) ? mw * mh : 0.f;
                float iou = inter / (tarea + aw * ah - inter);
                if (iou > best) { best = iou; bestn = n; }
            }
        }
        const unsigned long long vm = __ballot(valid);
        if (valid) {
            // compacted slot for the ignore loop (order irrelevant: OR-reduce)
            const int idx = __popcll(vm & ((1ull << tid) - 1ull));
            sm->box[idx] = make_float4(tx - tw*0.5f, ty - th*0.5f,
                                       tx + tw*0.5f, ty + th*0.5f);
            sm->thr[idx] = 0.7f * tarea;
            // winner metadata by original index
            const int gi = (int)tx, gj = (int)ty;
            sm->fx[tid] = tx - (float)gi;
            sm->fy[tid] = ty - (float)gj;
            const int bn = bestn % 3;
            const float awm = c_anchors[2*(3*GROUP + bn)]   * (1.f / STRIDE);
            const float ahm = c_anchors[2*(3*GROUP + bn)+1] * (1.f / STRIDE);
            sm->lw[tid] = logf(tw / awm + 1e-16f);
            sm->lh[tid] = logf(th / ahm + 1e-16f);
            sm->w2[tid] = 2.f - tarea / ((float)H * (float)H);
            // winner scatter target (drop semantics: OOB grid idx dropped)
            if (((bestn / 3) == GROUP) &&
                ((unsigned)gi < (unsigned)H) && ((unsigned)gj < (unsigned)H)) {
                const int ct = bn * HH + gj * H + gi;
                rel = ct - cb * 256;
                scat = (rel >= 0) && (rel < 256);
            }
        }
        if (tid == 0) sm->nval = __popcll(vm);
    }
    __syncthreads();                       // win[] init + meta visible
    if (scat) atomicMax(&sm->win[rel], tid);  // last-target-wins == max(t)
    __syncthreads();

    float local = 0.f;
    const int winner = sm->win[tid];       // -1 for all non-scattered cells

    // pred box (only meaningful for cell_ok lanes; zeros are NaN-free)
    float atlx = 0.f, atly = 0.f, abrx = 0.f, abry = 0.f, carea_a = 0.f;
    if (cell_ok) {
        const float s0 = 1.f / (1.f + expf(-x0));
        const float s1 = 1.f / (1.f + expf(-x1));
        const float manw = c_anchors[2*(3*GROUP + a)]   * (1.f / STRIDE);
        const float manh = c_anchors[2*(3*GROUP + a)+1] * (1.f / STRIDE);
        const float px = s0 + (float)i, py = s1 + (float)j;
        const float pw = expf(x2) * manw, ph = expf(x3) * manh;
        atlx = px - pw * 0.5f; atly = py - ph * 0.5f;
        abrx = px + pw * 0.5f; abry = py + ph * 0.5f;
        carea_a = 0.7f * (pw * ph);
    }

    // winner lanes never take the noobj branch; dead lanes contribute nothing:
    // pre-set ign so the wave-uniform early-exit can fire sooner.
    bool ign = (!cell_ok) || (winner >= 0);
    const int nval = sm->nval;             // E[nval] ~ 25.5 (vs fixed 50)

    // piou > 0.7  <=>  1.7*ai - 0.7*area_a > 0.7*area_b  (given overlap > 0)
    #define IGN_BODY(tt) {                                          \
        const float4 bx = sm->box[tt];                              \
        const float thr = sm->thr[tt];                              \
        const float tlx = fmaxf(atlx, bx.x);                        \
        const float tly = fmaxf(atly, bx.y);                        \
        const float brx = fminf(abrx, bx.z);                        \
        const float bry = fminf(abry, bx.w);                        \
        const float dx = brx - tlx, dy = bry - tly;                 \
        ign = ign || ((fminf(dx, dy) > 0.f) &&                      \
                      (fmaf(1.7f, dx * dy, -carea_a) > thr)); }

    int t = 0;
    while (t + 4 <= nval) {
        if (__all(ign)) break;             // wave-uniform: cheap scalar check
        IGN_BODY(t) IGN_BODY(t+1) IGN_BODY(t+2) IGN_BODY(t+3)
        t += 4;
    }
    if (!__all(ign))
        for (; t < nval; ++t) IGN_BODY(t)
    #undef IGN_BODY

    if (winner >= 0) {
        local += softplusf(-x4);                     // objectness target = 1
        const float w2v = sm->w2[winner];
        local += w2v * (bcef(x0, sm->fx[winner]) + bcef(x1, sm->fy[winner]));
        const float dw = x2 - sm->lw[winner];
        const float dh = x3 - sm->lh[winner];
        local += 0.5f * w2v * (dw * dw + dh * dh);
    } else if (!ign) {                               // implies cell_ok
        local += softplusf(x4);                      // objectness target = 0
    }
    return local;
}

// class loss for one (target, batch, layer) unit, handled by one wave
__device__ float class_unit(const float* __restrict__ r0,
                            const float* __restrict__ r1,
                            const float* __restrict__ r2,
                            const float* __restrict__ targets,
                            int u, int lane)
{
    const int L   = u / (T_TGT * NBATCH);
    const int rem = u - L * (T_TGT * NBATCH);
    const int b   = rem / T_TGT;
    const int t0  = rem - b * T_TGT;

    const int Hs[3] = {19, 38, 76};
    const float inv_s[3] = {1.f/32.f, 1.f/16.f, 1.f/8.f};
    const int Gs[3] = {2, 1, 0};
    const float* raw = (L == 0) ? r0 : (L == 1) ? r1 : r2;
    const int H = Hs[L];
    const int HH = H * H;
    const float is = inv_s[L];
    const int group = Gs[L];

    int selkey = 0x40000000 | lane;   // sentinel, never matches a real key
    int clsid = 0;
    if (lane < T_TGT) {
        const float* lab = targets + ((size_t)b * T_TGT + lane) * 5;
        float cf = lab[0], x = lab[1], y = lab[2], w = lab[3], h = lab[4];
        bool valid = (cf + x + y + w + h) > 0.f;
        float fs = (float)H;
        float tx = x * fs, ty = y * fs, tw = w * fs, th = h * fs;
        float tarea = tw * th;
        float best = -1.f; int bestn = 0;
        #pragma unroll
        for (int n = 0; n < 9; n++) {
            float aw = c_anchors[2*n] * is, ah = c_anchors[2*n+1] * is;
            float mw = fminf(tw, aw), mh = fminf(th, ah);
            float inter = (mw > 0.f && mh > 0.f) ? mw * mh : 0.f;
            float iou = inter / (tarea + aw * ah - inter);
            if (iou > best) { best = iou; bestn = n; }
        }
        if (valid && (bestn / 3) == group) {
            int bn = bestn % 3, gi = (int)tx, gj = (int)ty;
            selkey = (bn << 20) | (gj << 10) | gi;
        }
        clsid = (int)cf;
    }

    const int k0 = __shfl(selkey, t0);
    bool active = !(k0 & 0x40000000);                 // t0 selected?
    unsigned long long dup = __ballot(selkey == k0);
    active = active && !(dup >> (t0 + 1));            // later target wins cell

    float local = 0.f;
    if (active) {   // wave-uniform branch
        const int cls0 = __shfl(clsid, t0);
        const int gi = k0 & 1023, gj = (k0 >> 10) & 1023, bn = k0 >> 20;
        const float* base = raw + ((size_t)b * 255 + bn * 85) * HH + gj * H + gi;
        // class loss = sum_c softplus(x_c) - x_cls
        float xc = base[(size_t)(5 + lane) * HH];               // classes 0..63
        local = softplusf(xc) - ((lane == cls0) ? xc : 0.f);
        if (lane < 16) {
            float xh = base[(size_t)(69 + lane) * HH];          // classes 64..79
            local += softplusf(xh) - ((lane + 64 == cls0) ? xh : 0.f);
        }
    }
    return local;
}

__global__ __launch_bounds__(256)
void yolo_fused(const float* __restrict__ r0,
                const float* __restrict__ r1,
                const float* __restrict__ r2,
                const float* __restrict__ targets,
                float* __restrict__ partial)
{
    __shared__ SmemMain sm;
    __shared__ float s_wsum[4];

    const int blk = blockIdx.x;
    const int tid = threadIdx.x;
    float local = 0.f;

    if (blk < NB_L0 * NBATCH) {
        int b = blk / NB_L0, cb = blk - b * NB_L0;
        local = main_cells<19, 32, 2>(r0, targets, b, cb, tid, &sm);
    } else if (blk < (NB_L0 + NB_L1) * NBATCH) {
        int q = blk - NB_L0 * NBATCH;
        int b = q / NB_L1, cb = q - b * NB_L1;
        local = main_cells<38, 16, 1>(r1, targets, b, cb, tid, &sm);
    } else if (blk < NB_MAIN) {
        int q = blk - (NB_L0 + NB_L1) * NBATCH;
        int b = q / NB_L2, cb = q - b * NB_L2;
        local = main_cells<76, 8, 0>(r2, targets, b, cb, tid, &sm);
    } else {
        int u = (blk - NB_MAIN) * 4 + (tid >> 6);
        if (u < N_CLS_UNITS)
            local = class_unit(r0, r1, r2, targets, u, tid & 63);
    }

    // block reduction -> unique partial slot (no global atomics)
    for (int off = 32; off > 0; off >>= 1)
        local += __shfl_down(local, off, 64);
    const int lane = tid & 63, wv = tid >> 6;
    if (lane == 0) s_wsum[wv] = local;
    __syncthreads();
    if (tid == 0)
        partial[blk] = s_wsum[0] + s_wsum[1] + s_wsum[2] + s_wsum[3];
}

__global__ __launch_bounds__(256)
void yolo_reduce(const float4* __restrict__ partial4, float* __restrict__ out)
{
    const int tid = threadIdx.x;
    constexpr int NV = NB_TOTAL / 4;    // 510 float4s (NB_TOTAL % 4 == 0)
    float4 v = partial4[tid];           // tid < 256 < NV
    float s = v.x + v.y + v.z + v.w;
    if (tid + 256 < NV) {
        float4 u = partial4[tid + 256];
        s += u.x + u.y + u.z + u.w;
    }
    for (int off = 32; off > 0; off >>= 1)
        s += __shfl_down(s, off, 64);
    __shared__ float w[4];
    if ((tid & 63) == 0) w[tid >> 6] = s;
    __syncthreads();
    if (tid == 0) out[0] = w[0] + w[1] + w[2] + w[3];
}

extern "C" void kernel_launch(void* const* d_in, const int* in_sizes, int n_in,
                              void* d_out, int out_size, void* d_ws, size_t ws_size,
                              hipStream_t stream)
{
    const float* out0 = (const float*)d_in[0];
    const float* out1 = (const float*)d_in[1];
    const float* out2 = (const float*)d_in[2];
    const float* tgt  = (const float*)d_in[3];
    float* out = (float*)d_out;
    float* partial = (float*)d_ws;   // NB_TOTAL floats, all slots written

    yolo_fused<<<NB_TOTAL, 256, 0, stream>>>(out0, out1, out2, tgt, partial);
    yolo_reduce<<<1, 256, 0, stream>>>((const float4*)partial, out);
}